// Round 15
// baseline (59.127 us; speedup 1.0000x reference)
//
#include <hip/hip_runtime.h>

// Transposed conv (stride 2, 4x4, pad 2) as bf16 MFMA implicit GEMM, v12.
// x: (32,256,32,32) f32, W: (128,256,4,4) OIHW f32, b: (128,), out: (32,128,64,64) f32
// y[n,o,2a+pi,2b+pj] = bias[o] + sum_{c,du,dv} W[o,c,pi+2du,pj+2dv] * x[n,c,a+pi-1+du,b+pj-1+dv]
//
// v12 = v5 geometry (128o x 64px waves: x-traffic frontier; best measured main)
//  + register diet to fit 3 waves/SIMD (acc 128 + xA 16 + ~24 = ~168 <= 170):
//    single x slot, loaded AFTER consumption (distance ~1 body >= 300 cyc)
//  + 3 W-buffer counted ledger (never vmcnt(0) in loop)
//  + v7's conflict-free epilogue remap (the ~3M conflicts were ALWAYS epilogue)
//  + fused prepack. Block: 256 thr, tile 128o x (4 arows x 32 b x 2 pj).

typedef float  f32x4  __attribute__((ext_vector_type(4)));
typedef short  short8 __attribute__((ext_vector_type(8)));
typedef unsigned short ushort4v __attribute__((ext_vector_type(4)));
typedef unsigned short ushort8v __attribute__((ext_vector_type(8)));

__device__ __forceinline__ unsigned short f2bf(float f) {
    unsigned u = __builtin_bit_cast(unsigned, f);
    u += 0x7fffu + ((u >> 16) & 1u);          // RNE (inputs finite)
    return (unsigned short)(u >> 16);
}

__device__ __forceinline__ void ld_lds16(const unsigned short* g, unsigned short* l) {
    __builtin_amdgcn_global_load_lds(
        (const __attribute__((address_space(1))) unsigned int*)g,
        (__attribute__((address_space(3))) unsigned int*)l,
        16, 0, 0);
}

// ---------------- layout constants (ushort units) ----------------
#define XP_U 288                 // per u' row: 36 v' * 8 c
#define XP_G 9792                // per (n,g): 34 * XP_U
#define XP_N 313344              // per n: 32 g * XP_G
#define WP_G 8192                // per (pi,g): 2 pj * 4 sub * 128 o * 8 c
#define WP_PI 262144             // 32 g * WP_G
#define WROW 1040                // LDS sh per (pj,sub) row: 128o*8c + 16 pad
#define WBUFS 8320               // 8 * WROW per chunk buffer

// ---------- fused prepack: grid (38, 32), 256 thr ----------
__global__ __launch_bounds__(256) void prepack_all(
    const float* __restrict__ x, const float* __restrict__ W,
    unsigned short* __restrict__ wp, unsigned short* __restrict__ xpp)
{
    const int tid = threadIdx.x;
    if (blockIdx.x >= 34) {
        int wid = (blockIdx.x - 34) * 32 + blockIdx.y;   // [0,128)
        int t = wid * 256 + tid;                          // (o,c)
        int o = t >> 8, c = t & 255;
        int g = c >> 3, c8 = c & 7;
        const float4* src = (const float4*)(W + (size_t)(o * 256 + c) * 16);
        float4 q0 = src[0], q1 = src[1], q2 = src[2], q3 = src[3];
        float rows[4][4] = {{q0.x,q0.y,q0.z,q0.w},{q1.x,q1.y,q1.z,q1.w},
                            {q2.x,q2.y,q2.z,q2.w},{q3.x,q3.y,q3.z,q3.w}};
        #pragma unroll
        for (int pi = 0; pi < 2; ++pi)
        #pragma unroll
        for (int pj = 0; pj < 2; ++pj)
        #pragma unroll
        for (int du = 0; du < 2; ++du)
        #pragma unroll
        for (int dv = 0; dv < 2; ++dv)
            wp[pi*WP_PI + g*WP_G + pj*4096 + (du*2+dv)*1024 + o*8 + c8] =
                f2bf(rows[pi+2*du][pj+2*dv]);
        return;
    }

    __shared__ unsigned short xt[256 * 32];   // [c][v] bf16, 16 KB
    const int up = blockIdx.x;                // u' in [0,34)
    const int n  = blockIdx.y;
    const bool interior = (up >= 1 && up <= 32);

    if (interior) {
        const int u = up - 1;
        #pragma unroll
        for (int k = 0; k < 8; ++k) {
            int idx4 = tid + k * 256;
            int c = idx4 >> 3, v4 = idx4 & 7;
            float4 val = *(const float4*)(x + ((size_t)(n*256 + c)*32 + u)*32 + v4*4);
            ushort4v s = { f2bf(val.x), f2bf(val.y), f2bf(val.z), f2bf(val.w) };
            *(ushort4v*)&xt[c*32 + v4*4] = s;
        }
        __syncthreads();
    }

    #pragma unroll
    for (int s = 0; s < 5; ++s) {
        int id = tid + s * 256;                // (g, v')
        if (id < 1152) {
            int g = id / 36, vp = id % 36;
            ushort8v o8 = {0,0,0,0,0,0,0,0};
            if (interior && vp >= 1 && vp <= 32) {      // v = vp-1 in [0,32)
                #pragma unroll
                for (int e = 0; e < 8; ++e)
                    o8[e] = xt[(g*8 + e)*32 + (vp - 1)];
            }
            *(ushort8v*)&xpp[(size_t)n*XP_N + g*XP_G + up*XP_U + vp*8] = o8;
        }
    }
}

// Main: grid 512 = (pi, aq in [0,8), n), XCD-swizzled; 256 thr = 4 waves
// (pjw = w>>1, half = w&1). Block tile: 128 o x (4 arows x 32 b x 2 pj).
// Wave: 128o x 64px -> acc[8][4] f32x4 = 128 regs.
__global__ __launch_bounds__(256, 3) void tconv_main(
    const unsigned short* __restrict__ xp,
    const unsigned short* __restrict__ wp,
    const float* __restrict__ bias,
    float* __restrict__ out)
{
    // W: 3 chunk-buffers x 8320 sh = 24960 sh = 49920 B -> 3 blocks/CU.
    // Epilogue (16.9 KB f32) overlays.
    __shared__ __align__(16) unsigned short lds[24960];

    const int tid  = threadIdx.x;
    const int lane = tid & 63;
    const int w    = tid >> 6;       // wave 0..3
    const int pjw  = w >> 1;
    const int half = w & 1;
    const int lg   = lane >> 4;      // sub = (du,dv)
    const int ln   = lane & 15;
    const int du   = lg >> 1, dv = lg & 1;

    const int bid = blockIdx.x;
    const int wg  = (bid & 7) * 64 + (bid >> 3);   // XCD swizzle (512 % 8 == 0)
    const int n   = wg >> 4;
    const int aq  = (wg >> 1) & 7;
    const int pi  = wg & 1;
    const int a0  = aq * 4;

    // per-lane x base (jj deltas are imm byte offsets {0,256,576,832})
    const unsigned short* xpb = xp + (size_t)n * XP_N + (a0 + pi) * XP_U
                              + ((half * 2 + du) * XP_U + (ln + pjw + dv) * 8);
    const unsigned short* wpb = wp + pi * WP_PI;

    const int wfoff = (pjw * 4 + lg) * WROW + ln * 8;

    f32x4 acc[8][4];
    #pragma unroll
    for (int i = 0; i < 8; ++i)
        #pragma unroll
        for (int jj = 0; jj < 4; ++jj)
            acc[i][jj] = (f32x4){0.f, 0.f, 0.f, 0.f};

    short8 xA[4];

// Stage chunk CH's W into buffer BUF: 4 DMA/wave (wave w: rows 2w,2w+1, 2 halves).
#define STAGE_W(CH, BUF)                                                     \
    { const unsigned short* ws_ = wpb + (size_t)(CH) * WP_G;                 \
      unsigned short* wd_ = lds + (BUF) * WBUFS;                             \
      _Pragma("unroll")                                                      \
      for (int s_ = 0; s_ < 4; ++s_) {                                       \
          int r_ = w * 2 + (s_ >> 1), h_ = s_ & 1;                           \
          ld_lds16(ws_ + r_ * 1024 + h_ * 512 + lane * 8,                    \
                   wd_ + r_ * WROW + h_ * 512 + lane * 8); } }

#define LOAD_X(CH)                                                           \
    { const unsigned short* xs_ = xpb + (size_t)(CH) * XP_G;                 \
      xA[0] = *(const short8*)(xs_);                                         \
      xA[1] = *(const short8*)(xs_ + 128);                                   \
      xA[2] = *(const short8*)(xs_ + XP_U);                                  \
      xA[3] = *(const short8*)(xs_ + XP_U + 128); }

// Body ch: hdr [vmcnt(VMN); barrier]; stage W(ch+2); 32 MFMA (implicit wait
// retires x(ch), which also retires W(ch+1) - issued long before, covered);
// then load x(ch+1) into the freed slot.
#define CHUNK(BUF, CH, VMN, DO_W, DO_X)                                      \
    {                                                                        \
        __builtin_amdgcn_sched_barrier(0);                                   \
        asm volatile("s_waitcnt vmcnt(" #VMN ")" ::: "memory");              \
        __builtin_amdgcn_s_barrier();                                        \
        __builtin_amdgcn_sched_barrier(0);                                   \
        if (DO_W) STAGE_W((CH) + 2, ((BUF) + 2) % 3);                        \
        const unsigned short* wb_ = lds + (BUF) * WBUFS + wfoff;             \
        __builtin_amdgcn_s_setprio(1);                                       \
        _Pragma("unroll")                                                    \
        for (int i_ = 0; i_ < 8; ++i_) {                                     \
            short8 av_ = *(const short8*)&wb_[i_ * 128];                     \
            _Pragma("unroll")                                                \
            for (int jj_ = 0; jj_ < 4; ++jj_)                                \
                acc[i_][jj_] = __builtin_amdgcn_mfma_f32_16x16x32_bf16(      \
                    av_, xA[jj_], acc[i_][jj_], 0, 0, 0);                    \
        }                                                                    \
        __builtin_amdgcn_s_setprio(0);                                       \
        if (DO_X) LOAD_X((CH) + 1);                                          \
    }

    // Prologue ledger: [W0:4, W1:4, x0:4] = 12 outstanding.
    STAGE_W(0, 0);
    STAGE_W(1, 1);
    __builtin_amdgcn_sched_barrier(0);
    LOAD_X(0);

    // Steady: body ch reads buf ch%3 (and xA = x(ch)), stages W(ch+2) into
    // buf (ch+2)%3 (== (ch-1)%3, freed at barrier), reloads xA = x(ch+1).
    for (int c6 = 0; c6 < 30; c6 += 6) {
        CHUNK(0, c6 + 0, 8, 1, 1);
        CHUNK(1, c6 + 1, 8, 1, 1);
        CHUNK(2, c6 + 2, 8, 1, 1);
        CHUNK(0, c6 + 3, 8, 1, 1);
        CHUNK(1, c6 + 4, 8, 1, 1);
        CHUNK(2, c6 + 5, 8, 1, 1);
    }
    // Tail: body 30 (no W-stage; loads x31), body 31 (drain).
    CHUNK(0, 30, 8, 0, 1);
    CHUNK(1, 31, 0, 0, 0);

#undef CHUNK
#undef LOAD_X
#undef STAGE_W

    __syncthreads();   // before LDS reuse by epilogue

    // Epilogue (v7-proven remap): write rows (r*4+lg) -> lg-quarters at bank
    // offsets 0/8/16/24 (conflict-free); float2-pair reads span all 32 banks.
    float* epi = (float*)lds;
    #pragma unroll
    for (int i = 0; i < 8; ++i) {
        __syncthreads();
        f32x4 bv = *(const f32x4*)&bias[i * 16 + lg * 4];
        #pragma unroll
        for (int jj = 0; jj < 4; ++jj) {
            int ar = half * 2 + (jj >> 1);
            int b  = (jj & 1) * 16 + ln;
            #pragma unroll
            for (int r = 0; r < 4; ++r)
                epi[((r * 4 + lg) * 8 + ar * 2 + pjw) * 33 + b] = acc[i][jj][r] + bv[r];
        }
        __syncthreads();
        #pragma unroll
        for (int k = 0; k < 4; ++k) {
            int f    = tid + k * 256;    // [0,1024) float4-store ids
            int row  = f >> 4;           // o_l'(row>>2) x ar(row&3)
            int q    = f & 15;
            float2 A = *(const float2*)&epi[(row * 2 + 0) * 33 + q * 2];
            float2 B = *(const float2*)&epi[(row * 2 + 1) * 33 + q * 2];
            float4 v = { A.x, B.x, A.y, B.y };
            int olp   = row >> 2;        // o_l' = r*4 + lg
            int o     = i * 16 + ((olp & 3) << 2) + (olp >> 2);   // o_l = lg*4+r
            int i_out = 2 * (a0 + (row & 3)) + pi;
            *(float4*)&out[(((size_t)n * 128 + o) * 64 + i_out) * 64 + q * 4] = v;
        }
    }
}

// =================== fallback: round-2 kernel (proven) ===================
__global__ __launch_bounds__(256) void prepack_w(const float* __restrict__ W,
                                                 unsigned short* __restrict__ Wp) {
    int t = blockIdx.x * 256 + threadIdx.x;
    int o = t >> 8, c = t & 255;
    const float4* src = (const float4*)(W + (size_t)(o * 256 + c) * 16);
    float4 q0 = src[0], q1 = src[1], q2 = src[2], q3 = src[3];
    float rows[4][4] = {{q0.x,q0.y,q0.z,q0.w},{q1.x,q1.y,q1.z,q1.w},
                        {q2.x,q2.y,q2.z,q2.w},{q3.x,q3.y,q3.z,q3.w}};
    #pragma unroll
    for (int pi = 0; pi < 2; ++pi)
    #pragma unroll
    for (int pj = 0; pj < 2; ++pj)
    #pragma unroll
    for (int du = 0; du < 2; ++du)
    #pragma unroll
    for (int dv = 0; dv < 2; ++dv)
        Wp[((((pi*2+pj)*4 + du*2+dv)*128 + o)*256) + c] = f2bf(rows[pi+2*du][pj+2*dv]);
}

template<bool PRE>
__global__ __launch_bounds__(512, 2) void tconv_mfma(
    const float* __restrict__ x, const float* __restrict__ W,
    const unsigned short* __restrict__ Wp, const float* __restrict__ bias,
    float* __restrict__ out)
{
    __shared__ __align__(16) unsigned short xsh[2][9 * 34 * 8];
    __shared__ __align__(16) unsigned short wsh[2][2 * 4 * 128 * 8];

    const int tid = threadIdx.x;
    const int bid = blockIdx.x;
    const int pi  = bid & 1;
    const int aq  = (bid >> 1) & 3;
    const int n   = bid >> 3;
    const int a0  = aq * 8;
    const int u0  = a0 + pi - 1;

    const int l   = tid & 63;
    const int w   = tid >> 6;
    const int pjw = w >> 2;
    const int q   = w & 3;
    const int lg  = l >> 4;
    const int ln  = l & 15;

    const int sv = tid & 31;
    const int sg = tid >> 5;

    f32x4 acc[8][4];
    #pragma unroll
    for (int i = 0; i < 8; ++i)
        #pragma unroll
        for (int jj = 0; jj < 4; ++jj)
            acc[i][jj] = (f32x4){0.f, 0.f, 0.f, 0.f};

    float    xv[5];
    ushort4v wv[4];
    float4   wa[2], wb[2];

    auto stage_load = [&](int ch) {
        const int c0 = ch * 8;
        #pragma unroll
        for (int s = 0; s < 5; ++s) {
            int p = sg * 5 + s;
            if (p < 72) {
                int c = p & 7, rr = p >> 3;
                int u = u0 + rr;
                xv[s] = ((unsigned)u < 32u)
                      ? x[((n*256 + c0 + c)*32 + u)*32 + sv] : 0.f;
            }
        }
        if (PRE) {
            #pragma unroll
            for (int k = 0; k < 4; ++k) {
                int uu = tid + k * 512;
                int chalf = uu & 1, o = (uu >> 1) & 127;
                int sub = (uu >> 8) & 3, pjq = (uu >> 10) & 1;
                wv[k] = *(const ushort4v*)&Wp[(((pi*2 + pjq)*4 + sub)*128 + o)*256
                                              + c0 + chalf*4];
            }
        } else {
            #pragma unroll
            for (int k = 0; k < 2; ++k) {
                int pr = tid + k * 512;
                int o = pr >> 3, c = pr & 7;
                const float* base = W + ((o*256 + c0 + c) << 4) + pi*4;
                wa[k] = *(const float4*)base;
                wb[k] = *(const float4*)(base + 8);
            }
        }
    };

    auto stage_write = [&](int buf) {
        #pragma unroll
        for (int s = 0; s < 5; ++s) {
            int p = sg * 5 + s;
            if (p < 72) {
                int c = p & 7, rr = p >> 3;
                xsh[buf][(rr*34 + sv + 1)*8 + c] = f2bf(xv[s]);
            }
        }
        if (tid < 144) {
            int pr = tid >> 1;
            int rr = pr >> 3, c = pr & 7;
            int cw = (tid & 1) * 33;
            xsh[buf][(rr*34 + cw)*8 + c] = 0;
        }
        if (PRE) {
            #pragma unroll
            for (int k = 0; k < 4; ++k) {
                int uu = tid + k * 512;
                int chalf = uu & 1, o = (uu >> 1) & 127;
                int sub = (uu >> 8) & 3, pjq = (uu >> 10) & 1;
                *(ushort4v*)&wsh[buf][(((pjq*4 + sub)*128 + o)*8) + chalf*4] = wv[k];
            }
        } else {
            #pragma unroll
            for (int k = 0; k < 2; ++k) {
                int pr = tid + k * 512;
                int o = pr >> 3, c = pr & 7;
                float ra[4] = {wa[k].x, wa[k].y, wa[k].z, wa[k].w};
                float rb[4] = {wb[k].x, wb[k].y, wb[k].z, wb[k].w};
                #pragma unroll
                for (int pj2 = 0; pj2 < 2; ++pj2)
                #pragma unroll
                for (int duu = 0; duu < 2; ++duu)
                #pragma unroll
                for (int dvv = 0; dvv < 2; ++dvv) {
                    float val = duu ? rb[pj2 + 2*dvv] : ra[pj2 + 2*dvv];
                    wsh[buf][(((pj2*4 + duu*2 + dvv)*128 + o)*8) + c] = f2bf(val);
                }
            }
        }
    };

    stage_load(0);
    stage_write(0);
    __syncthreads();

    for (int ch = 0; ch < 32; ++ch) {
        const int cur = ch & 1;
        if (ch + 1 < 32) stage_load(ch + 1);

        short8 bfr[4];
        #pragma unroll
        for (int jj = 0; jj < 4; ++jj) {
            int arow = q*2 + (jj >> 1);
            int b    = (jj & 1)*16 + ln;
            int rr   = arow + (lg >> 1);
            int cw   = b + pjw + (lg & 1);
            bfr[jj]  = *(const short8*)&xsh[cur][(rr*34 + cw)*8];
        }
        #pragma unroll
        for (int i = 0; i < 8; ++i) {
            short8 av = *(const short8*)&wsh[cur][((pjw*4 + lg)*128 + i*16 + ln)*8];
            #pragma unroll
            for (int jj = 0; jj < 4; ++jj)
                acc[i][jj] = __builtin_amdgcn_mfma_f32_16x16x32_bf16(
                                 av, bfr[jj], acc[i][jj], 0, 0, 0);
        }

        if (ch + 1 < 32) stage_write(cur ^ 1);
        __syncthreads();
    }

    #pragma unroll
    for (int i = 0; i < 8; ++i) {
        const f32x4 bv = *(const f32x4*)&bias[i*16 + lg*4];
        #pragma unroll
        for (int jj = 0; jj < 4; ++jj) {
            int arow  = q*2 + (jj >> 1);
            int b     = (jj & 1)*16 + ln;
            int i_out = 2*(a0 + arow) + pi;
            int j_out = 2*b + pjw;
            int o0    = i*16 + lg*4;
            int base  = ((n*128 + o0)*64 + i_out)*64 + j_out;
            #pragma unroll
            for (int r = 0; r < 4; ++r)
                out[base + r*4096] = acc[i][jj][r] + bv[r];
        }
    }
}

extern "C" void kernel_launch(void* const* d_in, const int* in_sizes, int n_in,
                              void* d_out, int out_size, void* d_ws, size_t ws_size,
                              hipStream_t stream) {
    const float* x    = (const float*)d_in[0];
    const float* W    = (const float*)d_in[1];
    const float* bias = (const float*)d_in[2];
    float* out        = (float*)d_out;

    const size_t wp2_bytes = (size_t)2 * WP_PI * 2;          // 1 MB
    const size_t xp_bytes  = (size_t)32 * XP_N * 2;          // ~20 MB
    if (ws_size >= wp2_bytes + xp_bytes) {
        unsigned short* wp2 = (unsigned short*)d_ws;
        unsigned short* xpp = (unsigned short*)((char*)d_ws + wp2_bytes);
        prepack_all<<<dim3(38, 32), 256, 0, stream>>>(x, W, wp2, xpp);
        tconv_main<<<512, 256, 0, stream>>>(xpp, wp2, bias, out);
    } else if (ws_size >= (size_t)4*4*128*256*2) {
        unsigned short* Wp = (unsigned short*)d_ws;
        prepack_w<<<128, 256, 0, stream>>>(W, Wp);
        tconv_mfma<true><<<256, 512, 0, stream>>>(x, W, Wp, bias, out);
    } else {
        tconv_mfma<false><<<256, 512, 0, stream>>>(x, W, nullptr, bias, out);
    }
}

// Round 16
// 55.887 us; speedup vs baseline: 1.0580x; 1.0580x over previous
//
#include <hip/hip_runtime.h>

// Transposed conv (stride 2, 4x4, pad 2) as bf16 MFMA implicit GEMM, v13.
// x: (32,256,32,32) f32, W: (128,256,4,4) OIHW f32, b: (128,), out: (32,128,64,64) f32
// y[n,o,2a+pi,2b+pj] = bias[o] + sum_{c,du,dv} W[o,c,pi+2du,pj+2dv] * x[n,c,a+pi-1+du,b+pj-1+dv]
//
// v13 = v5 EXACT structure (best measured main, 40.7us: 128o x 64px waves,
// 4-buffer W pipeline distance-3, x ping-pong distance-2, vmcnt(8) ledger,
// launch_bounds(256,2)) + three isolated proven fixes:
//   1) W LDS row stride 1040 -> 1024 (unpadded): conflicts 2.75M->655K
//      (evidence: v8/v9 [512-stride] vs v5/v7/v11/v12 [padded])
//   2) v7-proven conflict-free epilogue remap (float2-pair reads)
//   3) s_setprio(1) around MFMA clusters (2 co-resident blocks = role diversity)
//   + fused prepack (one launch).

typedef float  f32x4  __attribute__((ext_vector_type(4)));
typedef short  short8 __attribute__((ext_vector_type(8)));
typedef unsigned short ushort4v __attribute__((ext_vector_type(4)));
typedef unsigned short ushort8v __attribute__((ext_vector_type(8)));

__device__ __forceinline__ unsigned short f2bf(float f) {
    unsigned u = __builtin_bit_cast(unsigned, f);
    u += 0x7fffu + ((u >> 16) & 1u);          // RNE (inputs finite)
    return (unsigned short)(u >> 16);
}

__device__ __forceinline__ void ld_lds16(const unsigned short* g, unsigned short* l) {
    __builtin_amdgcn_global_load_lds(
        (const __attribute__((address_space(1))) unsigned int*)g,
        (__attribute__((address_space(3))) unsigned int*)l,
        16, 0, 0);
}

// ---------------- layout constants (ushort units) ----------------
#define XP_U 288                 // per u' row: 36 v' * 8 c
#define XP_G 9792                // per (n,g): 34 * XP_U
#define XP_N 313344              // per n: 32 g * XP_G
#define WP_G 8192                // per (pi,g): 2 pj * 4 sub * 128 o * 8 c
#define WP_PI 262144             // 32 g * WP_G
#define WROW 1024                // LDS sh per (pj,sub) row: UNPADDED (conflict fix)
#define WBUFS 8192               // 8 * WROW per chunk buffer

// ---------- fused prepack: grid (38, 32), 256 thr ----------
// blocks up<34: prepack_x(up, n);  up>=34: prepack_w2 id = (up-34)*32 + n.
__global__ __launch_bounds__(256) void prepack_all(
    const float* __restrict__ x, const float* __restrict__ W,
    unsigned short* __restrict__ wp, unsigned short* __restrict__ xpp)
{
    const int tid = threadIdx.x;
    if (blockIdx.x >= 34) {
        int wid = (blockIdx.x - 34) * 32 + blockIdx.y;   // [0,128)
        int t = wid * 256 + tid;                          // (o,c)
        int o = t >> 8, c = t & 255;
        int g = c >> 3, c8 = c & 7;
        const float4* src = (const float4*)(W + (size_t)(o * 256 + c) * 16);
        float4 q0 = src[0], q1 = src[1], q2 = src[2], q3 = src[3];
        float rows[4][4] = {{q0.x,q0.y,q0.z,q0.w},{q1.x,q1.y,q1.z,q1.w},
                            {q2.x,q2.y,q2.z,q2.w},{q3.x,q3.y,q3.z,q3.w}};
        #pragma unroll
        for (int pi = 0; pi < 2; ++pi)
        #pragma unroll
        for (int pj = 0; pj < 2; ++pj)
        #pragma unroll
        for (int du = 0; du < 2; ++du)
        #pragma unroll
        for (int dv = 0; dv < 2; ++dv)
            wp[pi*WP_PI + g*WP_G + pj*4096 + (du*2+dv)*1024 + o*8 + c8] =
                f2bf(rows[pi+2*du][pj+2*dv]);
        return;
    }

    __shared__ unsigned short xt[256 * 32];   // [c][v] bf16, 16 KB
    const int up = blockIdx.x;                // u' in [0,34)
    const int n  = blockIdx.y;
    const bool interior = (up >= 1 && up <= 32);

    if (interior) {
        const int u = up - 1;
        #pragma unroll
        for (int k = 0; k < 8; ++k) {
            int idx4 = tid + k * 256;
            int c = idx4 >> 3, v4 = idx4 & 7;
            float4 val = *(const float4*)(x + ((size_t)(n*256 + c)*32 + u)*32 + v4*4);
            ushort4v s = { f2bf(val.x), f2bf(val.y), f2bf(val.z), f2bf(val.w) };
            *(ushort4v*)&xt[c*32 + v4*4] = s;
        }
        __syncthreads();
    }

    #pragma unroll
    for (int s = 0; s < 5; ++s) {
        int id = tid + s * 256;                // (g, v')
        if (id < 1152) {
            int g = id / 36, vp = id % 36;
            ushort8v o8 = {0,0,0,0,0,0,0,0};
            if (interior && vp >= 1 && vp <= 32) {      // v = vp-1 in [0,32)
                #pragma unroll
                for (int e = 0; e < 8; ++e)
                    o8[e] = xt[(g*8 + e)*32 + (vp - 1)];
            }
            *(ushort8v*)&xpp[(size_t)n*XP_N + g*XP_G + up*XP_U + vp*8] = o8;
        }
    }
}

// Main: grid 512 = (pi, aq in [0,8), n) XCD-swizzled; 256 thr = 4 waves (pjw, half).
// Block tile: 128 o x (4 arows x 32 b x 2 pj). Wave: 128o x 64px.
__global__ __launch_bounds__(256, 2) void tconv_main(
    const unsigned short* __restrict__ xp,
    const unsigned short* __restrict__ wp,
    const float* __restrict__ bias,
    float* __restrict__ out)
{
    // W only: 4 buffers x 8192 sh = 32768 sh = 65536 B.
    // Epilogue epi (16.9 KB f32) overlays buffer space.
    __shared__ __align__(16) unsigned short lds[32768];
    unsigned short* wsh0 = lds;

    const int tid  = threadIdx.x;
    const int lane = tid & 63;
    const int w    = tid >> 6;       // wave 0..3
    const int pjw  = w >> 1;
    const int half = w & 1;
    const int lg   = lane >> 4;      // sub = (du,dv)
    const int ln   = lane & 15;
    const int du   = lg >> 1, dv = lg & 1;

    const int bid = blockIdx.x;
    const int wg  = (bid & 7) * 64 + (bid >> 3);   // XCD swizzle (512 % 8 == 0)
    const int n   = wg >> 4;
    const int aq  = (wg >> 1) & 7;
    const int pi  = wg & 1;
    const int a0  = aq * 4;

    const unsigned short* xpb = xp + (size_t)n * XP_N + (a0 + pi) * XP_U;
    const unsigned short* wpb = wp + pi * WP_PI;

    // per-lane fragment offsets (static after unroll)
    int xoff[4];
    #pragma unroll
    for (int jj = 0; jj < 4; ++jj) {
        int rr = half * 2 + (jj >> 1) + du;
        int vv = (jj & 1) * 16 + ln + pjw + dv;
        xoff[jj] = rr * XP_U + vv * 8;
    }
    const int wfoff = (pjw * 4 + lg) * WROW + ln * 8;

    f32x4 acc[8][4];
    #pragma unroll
    for (int i = 0; i < 8; ++i)
        #pragma unroll
        for (int jj = 0; jj < 4; ++jj)
            acc[i][jj] = (f32x4){0.f, 0.f, 0.f, 0.f};

    short8 xA[4], xB[4];

#define STAGE_W(CH, WBUF)                                                    \
    { const unsigned short* ws_ = wpb + (size_t)(CH) * WP_G;                 \
      unsigned short* wd_ = wsh0 + (WBUF) * WBUFS;                           \
      _Pragma("unroll")                                                      \
      for (int s_ = 0; s_ < 4; ++s_) {                                       \
          int r_ = w * 2 + (s_ >> 1), h_ = s_ & 1;                           \
          ld_lds16(ws_ + r_ * 1024 + h_ * 512 + lane * 8,                    \
                   wd_ + r_ * WROW + h_ * 512 + lane * 8); } }

#define LOAD_X(CH, XS)                                                      \
    { const unsigned short* xs_ = xpb + (size_t)(CH) * XP_G;                 \
      _Pragma("unroll")                                                      \
      for (int jj_ = 0; jj_ < 4; ++jj_)                                      \
          XS[jj_] = *(const short8*)(xs_ + xoff[jj_]); }

// Body: wait vmcnt(VMN); barrier; [issue W(CH+3)]; MFMA (setprio); [issue x(CH+2)]
#define CHUNK(BUF, XS, CH, VMN, DO_W, DO_X)                                  \
    {                                                                        \
        __builtin_amdgcn_sched_barrier(0);                                   \
        asm volatile("s_waitcnt vmcnt(" #VMN ")" ::: "memory");              \
        __builtin_amdgcn_s_barrier();                                        \
        __builtin_amdgcn_sched_barrier(0);                                   \
        if (DO_W) STAGE_W((CH) + 3, ((BUF) + 3) & 3);                        \
        const unsigned short* wb_ = wsh0 + (BUF) * WBUFS + wfoff;            \
        __builtin_amdgcn_s_setprio(1);                                       \
        _Pragma("unroll")                                                    \
        for (int i_ = 0; i_ < 8; ++i_) {                                     \
            short8 av_ = *(const short8*)&wb_[i_ * 128];                     \
            _Pragma("unroll")                                                \
            for (int jj_ = 0; jj_ < 4; ++jj_)                                \
                acc[i_][jj_] = __builtin_amdgcn_mfma_f32_16x16x32_bf16(      \
                    av_, XS[jj_], acc[i_][jj_], 0, 0, 0);                    \
        }                                                                    \
        __builtin_amdgcn_s_setprio(0);                                       \
        if (DO_X) LOAD_X((CH) + 2, XS);                                      \
    }

    // Prologue — issue order defines the vmcnt ledger:
    // [W0, W1, x0, W2, x1] -> first wait vmcnt(8) retires W0,W1,x0.
    STAGE_W(0, 0);
    STAGE_W(1, 1);
    __builtin_amdgcn_sched_barrier(0);
    LOAD_X(0, xA);
    __builtin_amdgcn_sched_barrier(0);
    STAGE_W(2, 2);
    __builtin_amdgcn_sched_barrier(0);
    LOAD_X(1, xB);
    __builtin_amdgcn_sched_barrier(0);

    for (int ch4 = 0; ch4 < 28; ch4 += 4) {
        CHUNK(0, xA, ch4 + 0, 8, 1, 1);
        CHUNK(1, xB, ch4 + 1, 8, 1, 1);
        CHUNK(2, xA, ch4 + 2, 8, 1, 1);
        CHUNK(3, xB, ch4 + 3, 8, 1, 1);
    }
    // Tail: ch=28 issues W31+x30; ch=29 issues x31; ch=30/31 drain.
    CHUNK(0, xA, 28, 8, 1, 1);
    CHUNK(1, xB, 29, 8, 0, 1);
    CHUNK(2, xA, 30, 4, 0, 0);
    CHUNK(3, xB, 31, 0, 0, 0);

#undef CHUNK
#undef LOAD_X
#undef STAGE_W

    __syncthreads();   // all K-loop LDS reads complete before overlay reuse

    // Epilogue (v7-proven remap): write rows (r*4+lg) -> lg-quarters at bank
    // offsets 0/8/16/24 (conflict-free); float2-pair reads span all 32 banks.
    float* epi = (float*)lds;
    #pragma unroll
    for (int i = 0; i < 8; ++i) {
        __syncthreads();
        f32x4 bv = *(const f32x4*)&bias[i * 16 + lg * 4];
        #pragma unroll
        for (int jj = 0; jj < 4; ++jj) {
            int ar = half * 2 + (jj >> 1);
            int b  = (jj & 1) * 16 + ln;
            #pragma unroll
            for (int r = 0; r < 4; ++r)
                epi[((r * 4 + lg) * 8 + ar * 2 + pjw) * 33 + b] = acc[i][jj][r] + bv[r];
        }
        __syncthreads();
        #pragma unroll
        for (int k = 0; k < 4; ++k) {
            int f    = tid + k * 256;    // [0,1024) float4-store ids
            int row  = f >> 4;           // o_l'(row>>2) x ar(row&3)
            int q    = f & 15;
            float2 A = *(const float2*)&epi[(row * 2 + 0) * 33 + q * 2];
            float2 B = *(const float2*)&epi[(row * 2 + 1) * 33 + q * 2];
            float4 v = { A.x, B.x, A.y, B.y };
            int olp   = row >> 2;        // o_l' = r*4 + lg
            int o     = i * 16 + ((olp & 3) << 2) + (olp >> 2);   // o_l = lg*4+r
            int i_out = 2 * (a0 + (row & 3)) + pi;
            *(float4*)&out[(((size_t)n * 128 + o) * 64 + i_out) * 64 + q * 4] = v;
        }
    }
}

// =================== fallback: round-2 kernel (proven) ===================
__global__ __launch_bounds__(256) void prepack_w(const float* __restrict__ W,
                                                 unsigned short* __restrict__ Wp) {
    int t = blockIdx.x * 256 + threadIdx.x;
    int o = t >> 8, c = t & 255;
    const float4* src = (const float4*)(W + (size_t)(o * 256 + c) * 16);
    float4 q0 = src[0], q1 = src[1], q2 = src[2], q3 = src[3];
    float rows[4][4] = {{q0.x,q0.y,q0.z,q0.w},{q1.x,q1.y,q1.z,q1.w},
                        {q2.x,q2.y,q2.z,q2.w},{q3.x,q3.y,q3.z,q3.w}};
    #pragma unroll
    for (int pi = 0; pi < 2; ++pi)
    #pragma unroll
    for (int pj = 0; pj < 2; ++pj)
    #pragma unroll
    for (int du = 0; du < 2; ++du)
    #pragma unroll
    for (int dv = 0; dv < 2; ++dv)
        Wp[((((pi*2+pj)*4 + du*2+dv)*128 + o)*256) + c] = f2bf(rows[pi+2*du][pj+2*dv]);
}

template<bool PRE>
__global__ __launch_bounds__(512, 2) void tconv_mfma(
    const float* __restrict__ x, const float* __restrict__ W,
    const unsigned short* __restrict__ Wp, const float* __restrict__ bias,
    float* __restrict__ out)
{
    __shared__ __align__(16) unsigned short xsh[2][9 * 34 * 8];
    __shared__ __align__(16) unsigned short wsh[2][2 * 4 * 128 * 8];

    const int tid = threadIdx.x;
    const int bid = blockIdx.x;
    const int pi  = bid & 1;
    const int aq  = (bid >> 1) & 3;
    const int n   = bid >> 3;
    const int a0  = aq * 8;
    const int u0  = a0 + pi - 1;

    const int l   = tid & 63;
    const int w   = tid >> 6;
    const int pjw = w >> 2;
    const int q   = w & 3;
    const int lg  = l >> 4;
    const int ln  = l & 15;

    const int sv = tid & 31;
    const int sg = tid >> 5;

    f32x4 acc[8][4];
    #pragma unroll
    for (int i = 0; i < 8; ++i)
        #pragma unroll
        for (int jj = 0; jj < 4; ++jj)
            acc[i][jj] = (f32x4){0.f, 0.f, 0.f, 0.f};

    float    xv[5];
    ushort4v wv[4];
    float4   wa[2], wb[2];

    auto stage_load = [&](int ch) {
        const int c0 = ch * 8;
        #pragma unroll
        for (int s = 0; s < 5; ++s) {
            int p = sg * 5 + s;
            if (p < 72) {
                int c = p & 7, rr = p >> 3;
                int u = u0 + rr;
                xv[s] = ((unsigned)u < 32u)
                      ? x[((n*256 + c0 + c)*32 + u)*32 + sv] : 0.f;
            }
        }
        if (PRE) {
            #pragma unroll
            for (int k = 0; k < 4; ++k) {
                int uu = tid + k * 512;
                int chalf = uu & 1, o = (uu >> 1) & 127;
                int sub = (uu >> 8) & 3, pjq = (uu >> 10) & 1;
                wv[k] = *(const ushort4v*)&Wp[(((pi*2 + pjq)*4 + sub)*128 + o)*256
                                              + c0 + chalf*4];
            }
        } else {
            #pragma unroll
            for (int k = 0; k < 2; ++k) {
                int pr = tid + k * 512;
                int o = pr >> 3, c = pr & 7;
                const float* base = W + ((o*256 + c0 + c) << 4) + pi*4;
                wa[k] = *(const float4*)base;
                wb[k] = *(const float4*)(base + 8);
            }
        }
    };

    auto stage_write = [&](int buf) {
        #pragma unroll
        for (int s = 0; s < 5; ++s) {
            int p = sg * 5 + s;
            if (p < 72) {
                int c = p & 7, rr = p >> 3;
                xsh[buf][(rr*34 + sv + 1)*8 + c] = f2bf(xv[s]);
            }
        }
        if (tid < 144) {
            int pr = tid >> 1;
            int rr = pr >> 3, c = pr & 7;
            int cw = (tid & 1) * 33;
            xsh[buf][(rr*34 + cw)*8 + c] = 0;
        }
        if (PRE) {
            #pragma unroll
            for (int k = 0; k < 4; ++k) {
                int uu = tid + k * 512;
                int chalf = uu & 1, o = (uu >> 1) & 127;
                int sub = (uu >> 8) & 3, pjq = (uu >> 10) & 1;
                *(ushort4v*)&wsh[buf][(((pjq*4 + sub)*128 + o)*8) + chalf*4] = wv[k];
            }
        } else {
            #pragma unroll
            for (int k = 0; k < 2; ++k) {
                int pr = tid + k * 512;
                int o = pr >> 3, c = pr & 7;
                float ra[4] = {wa[k].x, wa[k].y, wa[k].z, wa[k].w};
                float rb[4] = {wb[k].x, wb[k].y, wb[k].z, wb[k].w};
                #pragma unroll
                for (int pj2 = 0; pj2 < 2; ++pj2)
                #pragma unroll
                for (int duu = 0; duu < 2; ++duu)
                #pragma unroll
                for (int dvv = 0; dvv < 2; ++dvv) {
                    float val = duu ? rb[pj2 + 2*dvv] : ra[pj2 + 2*dvv];
                    wsh[buf][(((pj2*4 + duu*2 + dvv)*128 + o)*8) + c] = f2bf(val);
                }
            }
        }
    };

    stage_load(0);
    stage_write(0);
    __syncthreads();

    for (int ch = 0; ch < 32; ++ch) {
        const int cur = ch & 1;
        if (ch + 1 < 32) stage_load(ch + 1);

        short8 bfr[4];
        #pragma unroll
        for (int jj = 0; jj < 4; ++jj) {
            int arow = q*2 + (jj >> 1);
            int b    = (jj & 1)*16 + ln;
            int rr   = arow + (lg >> 1);
            int cw   = b + pjw + (lg & 1);
            bfr[jj]  = *(const short8*)&xsh[cur][(rr*34 + cw)*8];
        }
        #pragma unroll
        for (int i = 0; i < 8; ++i) {
            short8 av = *(const short8*)&wsh[cur][((pjw*4 + lg)*128 + i*16 + ln)*8];
            #pragma unroll
            for (int jj = 0; jj < 4; ++jj)
                acc[i][jj] = __builtin_amdgcn_mfma_f32_16x16x32_bf16(
                                 av, bfr[jj], acc[i][jj], 0, 0, 0);
        }

        if (ch + 1 < 32) stage_write(cur ^ 1);
        __syncthreads();
    }

    #pragma unroll
    for (int i = 0; i < 8; ++i) {
        const f32x4 bv = *(const f32x4*)&bias[i*16 + lg*4];
        #pragma unroll
        for (int jj = 0; jj < 4; ++jj) {
            int arow  = q*2 + (jj >> 1);
            int b     = (jj & 1)*16 + ln;
            int i_out = 2*(a0 + arow) + pi;
            int j_out = 2*b + pjw;
            int o0    = i*16 + lg*4;
            int base  = ((n*128 + o0)*64 + i_out)*64 + j_out;
            #pragma unroll
            for (int r = 0; r < 4; ++r)
                out[base + r*4096] = acc[i][jj][r] + bv[r];
        }
    }
}

extern "C" void kernel_launch(void* const* d_in, const int* in_sizes, int n_in,
                              void* d_out, int out_size, void* d_ws, size_t ws_size,
                              hipStream_t stream) {
    const float* x    = (const float*)d_in[0];
    const float* W    = (const float*)d_in[1];
    const float* bias = (const float*)d_in[2];
    float* out        = (float*)d_out;

    const size_t wp2_bytes = (size_t)2 * WP_PI * 2;          // 1 MB
    const size_t xp_bytes  = (size_t)32 * XP_N * 2;          // ~20 MB
    if (ws_size >= wp2_bytes + xp_bytes) {
        unsigned short* wp2 = (unsigned short*)d_ws;
        unsigned short* xpp = (unsigned short*)((char*)d_ws + wp2_bytes);
        prepack_all<<<dim3(38, 32), 256, 0, stream>>>(x, W, wp2, xpp);
        tconv_main<<<512, 256, 0, stream>>>(xpp, wp2, bias, out);
    } else if (ws_size >= (size_t)4*4*128*256*2) {
        unsigned short* Wp = (unsigned short*)d_ws;
        prepack_w<<<128, 256, 0, stream>>>(W, Wp);
        tconv_mfma<true><<<256, 512, 0, stream>>>(x, W, Wp, bias, out);
    } else {
        tconv_mfma<false><<<256, 512, 0, stream>>>(x, W, nullptr, bias, out);
    }
}